// Round 13
// baseline (457.735 us; speedup 1.0000x reference)
//
#include <hip/hip_runtime.h>

#define N_NODES 50000
#define N_EDGES 400000
#define DH 128
#define N_GRAPHS 256

#define SCAN_CHUNK 512
#define N_CHUNKS ((N_NODES + SCAN_CHUNK - 1) / SCAN_CHUNK)   // 98
#define ATTN_BLOCKS ((N_NODES + 15) / 16)                    // 3125
#define POOL_CHUNKS ((N_NODES + 63) / 64)                    // 782

typedef __bf16 bf16x8 __attribute__((ext_vector_type(8)));
typedef float f32x4 __attribute__((ext_vector_type(4)));
typedef _Float16 f16x2 __attribute__((ext_vector_type(2)));
typedef _Float16 f16x8 __attribute__((ext_vector_type(8)));

#define DEV __device__ __forceinline__

#if defined(__has_builtin)
#if __has_builtin(__builtin_amdgcn_fdot2)
#define HAS_FDOT2 1
#endif
#endif

DEV float fdot2acc(f16x2 a, f16x2 b, float c) {
#ifdef HAS_FDOT2
  return __builtin_amdgcn_fdot2(a, b, c, false);
#else
  return (float)a.x * (float)b.x + (float)a.y * (float)b.y + c;
#endif
}

DEV unsigned short f2bf(float f) {
  union { float f; unsigned int i; } v; v.f = f;
  unsigned int x = v.i;
  unsigned int r = (x + 0x7fffu + ((x >> 16) & 1u)) >> 16;
  return (unsigned short)r;
}

// ---- weight repack into MFMA B-fragment order ------------------------------
struct WPtrs { const float* w[12]; };

__global__ void repack_kernel(WPtrs wp, unsigned short* __restrict__ WB) {
  int mat = blockIdx.y;
  int m = blockIdx.x * 256 + threadIdx.x;   // 0..16383
  int j = m & 7;
  int lane = (m >> 3) & 63;
  int ct = (m >> 9) & 7;
  int kk = m >> 12;
  int i = kk * 32 + (lane >> 4) * 8 + j;
  int o = ct * 16 + (lane & 15);
  WB[mat * 16384 + m] = f2bf(wp.w[mat][i * 128 + o]);
}

// ---------------- CSR build --------------------------------------------------
__global__ void deg_count(const int* __restrict__ ei, int* __restrict__ deg, int E) {
  int e = blockIdx.x * 256 + threadIdx.x;
  if (e < E) atomicAdd(&deg[ei[E + e]], 1);
}

__global__ __launch_bounds__(256) void scan_sum(const int* __restrict__ deg,
                                                int* __restrict__ partials, int N) {
  __shared__ int red[256];
  int b = blockIdx.x, t = threadIdx.x;
  int base = b * SCAN_CHUNK + t * 2;
  int s = 0;
  if (base + 1 < N) { int2 v = *reinterpret_cast<const int2*>(deg + base); s = v.x + v.y; }
  else if (base < N) s = deg[base];
  red[t] = s;
  __syncthreads();
  for (int off = 128; off; off >>= 1) {
    if (t < off) red[t] += red[t + off];
    __syncthreads();
  }
  if (t == 0) partials[b] = red[0];
}

__global__ __launch_bounds__(128) void scan_partials(int* __restrict__ partials) {
  __shared__ int s[128];
  int t = threadIdx.x;
  int v = (t < N_CHUNKS) ? partials[t] : 0;
  s[t] = v;
  __syncthreads();
  for (int off = 1; off < 128; off <<= 1) {
    int o = (t >= off) ? s[t - off] : 0;
    __syncthreads();
    s[t] += o;
    __syncthreads();
  }
  if (t < N_CHUNKS) partials[t] = s[t] - v;   // exclusive
}

__global__ __launch_bounds__(256) void scan_apply(const int* __restrict__ deg,
                                                  const int* __restrict__ partials,
                                                  int* __restrict__ rowptr,
                                                  int* __restrict__ cursor, int N, int E) {
  __shared__ int s[256];
  int b = blockIdx.x, t = threadIdx.x;
  int base = b * SCAN_CHUNK + t * 2;
  int d0 = 0, d1 = 0;
  if (base + 1 < N) { int2 v = *reinterpret_cast<const int2*>(deg + base); d0 = v.x; d1 = v.y; }
  else if (base < N) d0 = deg[base];
  int local = d0 + d1;
  s[t] = local;
  __syncthreads();
  for (int off = 1; off < 256; off <<= 1) {
    int o = (t >= off) ? s[t - off] : 0;
    __syncthreads();
    s[t] += o;
    __syncthreads();
  }
  int offp = partials[b] + s[t] - local;
  if (base < N)     { rowptr[base] = offp;          cursor[base] = offp; }
  if (base + 1 < N) { rowptr[base + 1] = offp + d0; cursor[base + 1] = offp + d0; }
  if (b == 0 && t == 0) rowptr[N] = E;
}

__global__ void csr_scatter(const int* __restrict__ ei, int* __restrict__ cursor,
                            int* __restrict__ adj, int E) {
  int e = blockIdx.x * 256 + threadIdx.x;
  if (e < E) {
    int dst = ei[E + e];
    int pos = atomicAdd(&cursor[dst], 1);
    adj[pos] = ei[e];
  }
}

// ---------------- fused projection GEMM: blockIdx.y selects proj pair --------
// mode 0: stage fp32 x -> bf16.  mode 1: stage fp16 H with BN+ReLU -> bf16.
struct GemmOut { _Float16* Y[4]; const float* bias[4]; };

#define LDP 136   // padded LDS row stride (bf16 elems)

__global__ __launch_bounds__(256) void gemm_proj(
    const float* __restrict__ Xf,
    const _Float16* __restrict__ Hin,
    const float* __restrict__ scale, const float* __restrict__ shift,
    const unsigned short* __restrict__ WB4,   // fragment-ordered, 4 mats x 16384
    GemmOut go, int useBN, int N)
{
  __shared__ __align__(16) unsigned short xs[64 * LDP];

  const int t = threadIdx.x;
  const int rowBase = blockIdx.x * 64;
  const int igc = (t & 15) * 8;

  if (useBN) {
    float4 sc0 = *reinterpret_cast<const float4*>(scale + igc);
    float4 sc1 = *reinterpret_cast<const float4*>(scale + igc + 4);
    float4 sh0 = *reinterpret_cast<const float4*>(shift + igc);
    float4 sh1 = *reinterpret_cast<const float4*>(shift + igc + 4);
#pragma unroll
    for (int j = 0; j < 4; ++j) {
      int v = t + 256 * j;
      int r = v >> 4;
      int grow = rowBase + r;
      ushort4 o0 = make_ushort4(0, 0, 0, 0), o1 = make_ushort4(0, 0, 0, 0);
      if (grow < N) {
        f16x8 hv = *reinterpret_cast<const f16x8*>(Hin + (size_t)grow * 128 + igc);
        o0.x = f2bf(fmaxf((float)hv[0] * sc0.x + sh0.x, 0.f));
        o0.y = f2bf(fmaxf((float)hv[1] * sc0.y + sh0.y, 0.f));
        o0.z = f2bf(fmaxf((float)hv[2] * sc0.z + sh0.z, 0.f));
        o0.w = f2bf(fmaxf((float)hv[3] * sc0.w + sh0.w, 0.f));
        o1.x = f2bf(fmaxf((float)hv[4] * sc1.x + sh1.x, 0.f));
        o1.y = f2bf(fmaxf((float)hv[5] * sc1.y + sh1.y, 0.f));
        o1.z = f2bf(fmaxf((float)hv[6] * sc1.z + sh1.z, 0.f));
        o1.w = f2bf(fmaxf((float)hv[7] * sc1.w + sh1.w, 0.f));
      }
      *reinterpret_cast<ushort4*>(&xs[r * LDP + igc]) = o0;
      *reinterpret_cast<ushort4*>(&xs[r * LDP + igc + 4]) = o1;
    }
  } else {
#pragma unroll
    for (int j = 0; j < 4; ++j) {
      int v = t + 256 * j;
      int r = v >> 4;
      int grow = rowBase + r;
      ushort4 o0 = make_ushort4(0, 0, 0, 0), o1 = make_ushort4(0, 0, 0, 0);
      if (grow < N) {
        float4 a = *reinterpret_cast<const float4*>(Xf + (size_t)grow * 128 + igc);
        float4 b = *reinterpret_cast<const float4*>(Xf + (size_t)grow * 128 + igc + 4);
        o0.x = f2bf(a.x); o0.y = f2bf(a.y); o0.z = f2bf(a.z); o0.w = f2bf(a.w);
        o1.x = f2bf(b.x); o1.y = f2bf(b.y); o1.z = f2bf(b.z); o1.w = f2bf(b.w);
      }
      *reinterpret_cast<ushort4*>(&xs[r * LDP + igc]) = o0;
      *reinterpret_cast<ushort4*>(&xs[r * LDP + igc + 4]) = o1;
    }
  }
  __syncthreads();

  const int wave = t >> 6;
  const int lane = t & 63;
  const int ln16 = lane & 15;
  const int quad = lane >> 4;
  const int r0 = wave * 16;

  bf16x8 afrag[4];
#pragma unroll
  for (int kk = 0; kk < 4; ++kk)
    afrag[kk] = *reinterpret_cast<const bf16x8*>(&xs[(r0 + ln16) * LDP + kk * 32 + quad * 8]);

  const int pbase = blockIdx.y * 2;
#pragma unroll
  for (int pp = 0; pp < 2; ++pp) {
    const int proj = pbase + pp;
    const unsigned short* __restrict__ WB = WB4 + proj * 16384;
    const float* __restrict__ bias = go.bias[proj];

    f32x4 acc[8] = {};
#pragma unroll
    for (int kk = 0; kk < 4; ++kk) {
#pragma unroll
      for (int ct = 0; ct < 8; ++ct) {
        bf16x8 b = *reinterpret_cast<const bf16x8*>(WB + ((kk * 8 + ct) * 64 + lane) * 8);
        acc[ct] = __builtin_amdgcn_mfma_f32_16x16x32_bf16(afrag[kk], b, acc[ct], 0, 0, 0);
      }
    }

    _Float16* __restrict__ Yh = go.Y[proj];
#pragma unroll
    for (int ct = 0; ct < 8; ++ct) {
      int col = ct * 16 + ln16;
      float bv = bias[col];
#pragma unroll
      for (int reg = 0; reg < 4; ++reg) {
        int grow = rowBase + r0 + quad * 4 + reg;
        if (grow < N) Yh[(size_t)grow * 128 + col] = (_Float16)(acc[ct][reg] + bv);
      }
    }
  }
}

// ---------------- fused per-node attention + BN partial stats ----------------
// 16 lanes per node (f16x8 = 16B/lane), 16 nodes per 256-thread block.
__global__ __launch_bounds__(256) void node_attn(
    const int* __restrict__ rowptr, const int* __restrict__ adj,
    const _Float16* __restrict__ Q, const _Float16* __restrict__ K,
    const _Float16* __restrict__ V, _Float16* __restrict__ H,
    float* __restrict__ Pbuf, int N)
{
  __shared__ float lsum[16][128];
  __shared__ float lsq[16][128];
  int t = threadIdx.x;
  int w = t >> 4, lane = t & 15;
  int n = blockIdx.x * 16 + w;
  bool valid = n < N;
  int nn = valid ? n : 0;
  int p0 = 0, p1 = 0;
  if (valid) { p0 = rowptr[n]; p1 = rowptr[n + 1]; }

  f16x8 qv = *reinterpret_cast<const f16x8*>(Q + (size_t)nn * 128 + lane * 8);
  f16x2 q0 = {qv[0], qv[1]}, q1 = {qv[2], qv[3]}, q2 = {qv[4], qv[5]}, q3 = {qv[6], qv[7]};

  float m = -INFINITY, s = 0.f;
  float acc[8] = {};

  int p = p0;
  for (; p + 1 < p1; p += 2) {
    int s0 = adj[p], s1 = adj[p + 1];
    f16x8 k0 = *reinterpret_cast<const f16x8*>(K + (size_t)s0 * 128 + lane * 8);
    f16x8 k1 = *reinterpret_cast<const f16x8*>(K + (size_t)s1 * 128 + lane * 8);
    float d0 = fdot2acc(q0, (f16x2){k0[0], k0[1]},
               fdot2acc(q1, (f16x2){k0[2], k0[3]},
               fdot2acc(q2, (f16x2){k0[4], k0[5]},
               fdot2acc(q3, (f16x2){k0[6], k0[7]}, 0.f))));
    float d1 = fdot2acc(q0, (f16x2){k1[0], k1[1]},
               fdot2acc(q1, (f16x2){k1[2], k1[3]},
               fdot2acc(q2, (f16x2){k1[4], k1[5]},
               fdot2acc(q3, (f16x2){k1[6], k1[7]}, 0.f))));
#pragma unroll
    for (int off = 8; off; off >>= 1) {
      d0 += __shfl_xor(d0, off, 16);
      d1 += __shfl_xor(d1, off, 16);
    }
    float l0 = d0 * 0.08838834764831845f;
    float l1 = d1 * 0.08838834764831845f;
    float mn = fmaxf(m, fmaxf(l0, l1));
    float sc = __expf(m - mn);
    float w0 = __expf(l0 - mn);
    float w1 = __expf(l1 - mn);
    f16x8 v0 = *reinterpret_cast<const f16x8*>(V + (size_t)s0 * 128 + lane * 8);
    f16x8 v1 = *reinterpret_cast<const f16x8*>(V + (size_t)s1 * 128 + lane * 8);
#pragma unroll
    for (int i = 0; i < 8; ++i)
      acc[i] = acc[i] * sc + w0 * (float)v0[i] + w1 * (float)v1[i];
    s = s * sc + w0 + w1;
    m = mn;
  }
  if (p < p1) {
    int s0 = adj[p];
    f16x8 k0 = *reinterpret_cast<const f16x8*>(K + (size_t)s0 * 128 + lane * 8);
    float d0 = fdot2acc(q0, (f16x2){k0[0], k0[1]},
               fdot2acc(q1, (f16x2){k0[2], k0[3]},
               fdot2acc(q2, (f16x2){k0[4], k0[5]},
               fdot2acc(q3, (f16x2){k0[6], k0[7]}, 0.f))));
#pragma unroll
    for (int off = 8; off; off >>= 1) d0 += __shfl_xor(d0, off, 16);
    float l0 = d0 * 0.08838834764831845f;
    float mn = fmaxf(m, l0);
    float sc = __expf(m - mn);
    float w0 = __expf(l0 - mn);
    f16x8 v0 = *reinterpret_cast<const f16x8*>(V + (size_t)s0 * 128 + lane * 8);
#pragma unroll
    for (int i = 0; i < 8; ++i)
      acc[i] = acc[i] * sc + w0 * (float)v0[i];
    s = s * sc + w0;
    m = mn;
  }

  float h[8];
#pragma unroll
  for (int i = 0; i < 8; ++i) h[i] = 0.f;
  if (valid) {
    float inv = 1.0f / (s + 1e-16f);
    f16x8 hh = *reinterpret_cast<const f16x8*>(H + (size_t)n * 128 + lane * 8);
    f16x8 ho;
#pragma unroll
    for (int i = 0; i < 8; ++i) {
      h[i] = (float)hh[i] + acc[i] * inv;
      ho[i] = (_Float16)h[i];
    }
    *reinterpret_cast<f16x8*>(H + (size_t)n * 128 + lane * 8) = ho;
  }

  // BN partial stats
#pragma unroll
  for (int i = 0; i < 8; i += 4) {
    float4 hv = make_float4(h[i], h[i + 1], h[i + 2], h[i + 3]);
    float4 h2 = make_float4(hv.x * hv.x, hv.y * hv.y, hv.z * hv.z, hv.w * hv.w);
    *reinterpret_cast<float4*>(&lsum[w][lane * 8 + i]) = hv;
    *reinterpret_cast<float4*>(&lsq[w][lane * 8 + i]) = h2;
  }
  __syncthreads();

  int f = t & 127;
  float a = 0.f;
  if (t < 128) {
#pragma unroll
    for (int n16 = 0; n16 < 16; ++n16) a += lsum[n16][f];
  } else {
#pragma unroll
    for (int n16 = 0; n16 < 16; ++n16) a += lsq[n16][f];
  }
  Pbuf[(size_t)blockIdx.x * 256 + t] = a;
}

// ---------------- BN reduce: ATTN_BLOCKS x 256 partials -> 64x256 -> scale/shift
__global__ __launch_bounds__(256) void bn_reduceA(const float* __restrict__ Pbuf,
                                                  float* __restrict__ partial) {
  int t = threadIdx.x;
  float s0 = 0.f, s1 = 0.f, s2 = 0.f, s3 = 0.f;
  int r = blockIdx.x;
  for (; r + 192 < ATTN_BLOCKS; r += 256) {
    s0 += Pbuf[(size_t)(r      ) * 256 + t];
    s1 += Pbuf[(size_t)(r +  64) * 256 + t];
    s2 += Pbuf[(size_t)(r + 128) * 256 + t];
    s3 += Pbuf[(size_t)(r + 192) * 256 + t];
  }
  for (; r < ATTN_BLOCKS; r += 64) s0 += Pbuf[(size_t)r * 256 + t];
  partial[blockIdx.x * 256 + t] = s0 + s1 + s2 + s3;
}

__global__ __launch_bounds__(256) void bn_reduceB(
    const float* __restrict__ partial,
    const float* __restrict__ gamma, const float* __restrict__ beta,
    float* __restrict__ scale, float* __restrict__ shift, int N)
{
  __shared__ float red[256];
  int t = threadIdx.x;
  float s0 = 0.f, s1 = 0.f, s2 = 0.f, s3 = 0.f;
#pragma unroll
  for (int r = 0; r < 64; r += 4) {
    s0 += partial[(r + 0) * 256 + t];
    s1 += partial[(r + 1) * 256 + t];
    s2 += partial[(r + 2) * 256 + t];
    s3 += partial[(r + 3) * 256 + t];
  }
  red[t] = s0 + s1 + s2 + s3;
  __syncthreads();
  if (t < 128) {
    float mean = red[t] / (float)N;
    float var = red[t + 128] / (float)N - mean * mean;
    var = fmaxf(var, 0.f);
    float sc = gamma[t] * rsqrtf(var + 1e-5f);
    scale[t] = sc;
    shift[t] = beta[t] - mean * sc;
  }
}

// ---------------- parallel pool: 64-row chunks, flush at graph boundaries ----
__global__ __launch_bounds__(256) void pool_chunk(
    const _Float16* __restrict__ H, const float* __restrict__ scale,
    const float* __restrict__ shift, const int* __restrict__ batch,
    float* __restrict__ pooled, int N)
{
  int f = threadIdx.x & 127, half = threadIdx.x >> 7;
  int base = blockIdx.x * 64;
  int lim = min(base + 64, N);
  float sc = scale[f], sh = shift[f];
  int curg = -1; float s = 0.f;
  for (int row = base + half; row < lim; row += 2) {
    int g = batch[row];
    if (g != curg) {
      if (curg >= 0) unsafeAtomicAdd(pooled + curg * 128 + f, s);
      curg = g; s = 0.f;
    }
    s += fmaxf((float)H[(size_t)row * 128 + f] * sc + sh, 0.f);
  }
  if (curg >= 0) unsafeAtomicAdd(pooled + curg * 128 + f, s);
}

// ---------------- final linear -----------------------------------------------
__global__ __launch_bounds__(64) void final_linear(
    const float* __restrict__ pooled, const int* __restrict__ batch,
    const float* __restrict__ Wlin, const float* __restrict__ blin,
    float* __restrict__ out, int N)
{
  int g = blockIdx.x;
  int c = threadIdx.x;
  int lo = 0, hi = N;
  while (lo < hi) { int mid = (lo + hi) >> 1; if (batch[mid] < g) lo = mid + 1; else hi = mid; }
  int start = lo;
  hi = N;
  while (lo < hi) { int mid = (lo + hi) >> 1; if (batch[mid] < g + 1) lo = mid + 1; else hi = mid; }
  float inv = 1.0f / fmaxf((float)(lo - start), 1.f);
  if (c < 20) {
    float acc = 0.f;
#pragma unroll 4
    for (int i = 0; i < 128; ++i)
      acc += pooled[g * 128 + i] * Wlin[i * 20 + c];
    out[g * 20 + c] = acc * inv + blin[c];
  }
}

// =============================================================================
extern "C" void kernel_launch(void* const* d_in, const int* in_sizes, int n_in,
                              void* d_out, int out_size, void* d_ws, size_t ws_size,
                              hipStream_t stream)
{
  const int N = N_NODES, E = N_EDGES, G = N_GRAPHS;

  const float* x = (const float*)d_in[0];
  const int* ei = (const int*)d_in[1];
  const int* batch = (const int*)d_in[2];
  const float* Wlin = (const float*)d_in[33];
  const float* blin = (const float*)d_in[34];

  char* ws = (char*)d_ws;
  size_t off = 0;
  auto alloc = [&](size_t bytes) -> void* {
    void* p = ws + off;
    off = (off + bytes + 255) & ~(size_t)255;
    return p;
  };
  unsigned short* WB = (unsigned short*)alloc(12 * 16384 * sizeof(unsigned short));
  _Float16* Qh  = (_Float16*)alloc((size_t)N * 128 * 2);
  _Float16* Kh  = (_Float16*)alloc((size_t)N * 128 * 2);
  _Float16* Vh  = (_Float16*)alloc((size_t)N * 128 * 2);
  _Float16* Hh  = (_Float16*)alloc((size_t)N * 128 * 2);
  int* deg      = (int*)alloc((size_t)N * 4);
  int* rowptr   = (int*)alloc((size_t)(N + 1) * 4);
  int* cursor   = (int*)alloc((size_t)N * 4);
  int* adj      = (int*)alloc((size_t)E * 4);
  int* partials = (int*)alloc((size_t)N_CHUNKS * 4);
  float* Pbuf   = (float*)alloc((size_t)ATTN_BLOCKS * 256 * 4);
  float* bnpart = (float*)alloc((size_t)64 * 256 * 4);
  float* scale  = (float*)alloc(128 * 4);
  float* shift  = (float*)alloc(128 * 4);
  float* pooled = (float*)alloc((size_t)G * 128 * 4);

  // ---- one-time per launch: weight repack, CSR build ----
  WPtrs wp;
  for (int L = 0; L < 3; ++L) {
    wp.w[L * 4 + 0] = (const float*)d_in[3 + L * 10 + 0];  // Wq
    wp.w[L * 4 + 1] = (const float*)d_in[3 + L * 10 + 2];  // Wk
    wp.w[L * 4 + 2] = (const float*)d_in[3 + L * 10 + 4];  // Wv
    wp.w[L * 4 + 3] = (const float*)d_in[3 + L * 10 + 6];  // Ws
  }
  repack_kernel<<<dim3(64, 12), 256, 0, stream>>>(wp, WB);

  hipMemsetAsync(deg, 0, (size_t)N * 4, stream);
  deg_count<<<(E + 255) / 256, 256, 0, stream>>>(ei, deg, E);
  scan_sum<<<N_CHUNKS, 256, 0, stream>>>(deg, partials, N);
  scan_partials<<<1, 128, 0, stream>>>(partials);
  scan_apply<<<N_CHUNKS, 256, 0, stream>>>(deg, partials, rowptr, cursor, N, E);
  csr_scatter<<<(E + 255) / 256, 256, 0, stream>>>(ei, cursor, adj, E);

  for (int L = 0; L < 3; ++L) {
    GemmOut go;
    go.Y[0] = Qh; go.Y[1] = Kh; go.Y[2] = Vh; go.Y[3] = Hh;
    go.bias[0] = (const float*)d_in[3 + L * 10 + 1];
    go.bias[1] = (const float*)d_in[3 + L * 10 + 3];
    go.bias[2] = (const float*)d_in[3 + L * 10 + 5];
    go.bias[3] = (const float*)d_in[3 + L * 10 + 7];
    gemm_proj<<<dim3((N + 63) / 64, 2), 256, 0, stream>>>(
        x, Hh, scale, shift, WB + L * 4 * 16384, go, (L > 0) ? 1 : 0, N);

    node_attn<<<ATTN_BLOCKS, 256, 0, stream>>>(rowptr, adj, Qh, Kh, Vh, Hh, Pbuf, N);

    bn_reduceA<<<64, 256, 0, stream>>>(Pbuf, bnpart);
    bn_reduceB<<<1, 256, 0, stream>>>(bnpart,
        (const float*)d_in[3 + L * 10 + 8],
        (const float*)d_in[3 + L * 10 + 9],
        scale, shift, N);

    if (L == 2) {
      hipMemsetAsync(pooled, 0, (size_t)G * 128 * 4, stream);
      pool_chunk<<<POOL_CHUNKS, 256, 0, stream>>>(Hh, scale, shift, batch, pooled, N);
      final_linear<<<G, 64, 0, stream>>>(pooled, batch, Wlin, blin, (float*)d_out, N);
    }
  }
}

// Round 14
// 453.783 us; speedup vs baseline: 1.0087x; 1.0087x over previous
//
#include <hip/hip_runtime.h>

#define N_NODES 50000
#define N_EDGES 400000
#define DH 128
#define N_GRAPHS 256

#define SCAN_CHUNK 512
#define N_CHUNKS ((N_NODES + SCAN_CHUNK - 1) / SCAN_CHUNK)   // 98
#define ATTN_BLOCKS ((N_NODES + 15) / 16)                    // 3125
#define POOL_CHUNKS ((N_NODES + 63) / 64)                    // 782

typedef __bf16 bf16x8 __attribute__((ext_vector_type(8)));
typedef float f32x4 __attribute__((ext_vector_type(4)));
typedef _Float16 f16x2 __attribute__((ext_vector_type(2)));
typedef _Float16 f16x8 __attribute__((ext_vector_type(8)));

#define DEV __device__ __forceinline__

#if defined(__has_builtin)
#if __has_builtin(__builtin_amdgcn_fdot2)
#define HAS_FDOT2 1
#endif
#endif

DEV float fdot2acc(f16x2 a, f16x2 b, float c) {
#ifdef HAS_FDOT2
  return __builtin_amdgcn_fdot2(a, b, c, false);
#else
  return (float)a.x * (float)b.x + (float)a.y * (float)b.y + c;
#endif
}

DEV unsigned short f2bf(float f) {
  union { float f; unsigned int i; } v; v.f = f;
  unsigned int x = v.i;
  unsigned int r = (x + 0x7fffu + ((x >> 16) & 1u)) >> 16;
  return (unsigned short)r;
}

// ---- weight repack into MFMA B-fragment order + init deg/counter ------------
struct WPtrs { const float* w[12]; };

__global__ void repack_kernel(WPtrs wp, unsigned short* __restrict__ WB,
                              int* __restrict__ deg, int* __restrict__ counter, int N) {
  int mat = blockIdx.y;
  int m = blockIdx.x * 256 + threadIdx.x;   // 0..16383
  int j = m & 7;
  int lane = (m >> 3) & 63;
  int ct = (m >> 9) & 7;
  int kk = m >> 12;
  int i = kk * 32 + (lane >> 4) * 8 + j;
  int o = ct * 16 + (lane & 15);
  WB[mat * 16384 + m] = f2bf(wp.w[mat][i * 128 + o]);
  if (mat == 0) {
    for (int idx = m; idx < N; idx += 16384) deg[idx] = 0;
    if (m == 0) *counter = 0;
  }
}

// ---------------- CSR build --------------------------------------------------
__global__ void deg_count(const int* __restrict__ ei, int* __restrict__ deg, int E) {
  int e = blockIdx.x * 256 + threadIdx.x;
  if (e < E) atomicAdd(&deg[ei[E + e]], 1);
}

__global__ __launch_bounds__(256) void scan_sum(const int* __restrict__ deg,
                                                int* __restrict__ partials, int N) {
  __shared__ int red[256];
  int b = blockIdx.x, t = threadIdx.x;
  int base = b * SCAN_CHUNK + t * 2;
  int s = 0;
  if (base + 1 < N) { int2 v = *reinterpret_cast<const int2*>(deg + base); s = v.x + v.y; }
  else if (base < N) s = deg[base];
  red[t] = s;
  __syncthreads();
  for (int off = 128; off; off >>= 1) {
    if (t < off) red[t] += red[t + off];
    __syncthreads();
  }
  if (t == 0) partials[b] = red[0];
}

__global__ __launch_bounds__(128) void scan_partials(int* __restrict__ partials) {
  __shared__ int s[128];
  int t = threadIdx.x;
  int v = (t < N_CHUNKS) ? partials[t] : 0;
  s[t] = v;
  __syncthreads();
  for (int off = 1; off < 128; off <<= 1) {
    int o = (t >= off) ? s[t - off] : 0;
    __syncthreads();
    s[t] += o;
    __syncthreads();
  }
  if (t < N_CHUNKS) partials[t] = s[t] - v;   // exclusive
}

__global__ __launch_bounds__(256) void scan_apply(const int* __restrict__ deg,
                                                  const int* __restrict__ partials,
                                                  int* __restrict__ rowptr,
                                                  int* __restrict__ cursor, int N, int E) {
  __shared__ int s[256];
  int b = blockIdx.x, t = threadIdx.x;
  int base = b * SCAN_CHUNK + t * 2;
  int d0 = 0, d1 = 0;
  if (base + 1 < N) { int2 v = *reinterpret_cast<const int2*>(deg + base); d0 = v.x; d1 = v.y; }
  else if (base < N) d0 = deg[base];
  int local = d0 + d1;
  s[t] = local;
  __syncthreads();
  for (int off = 1; off < 256; off <<= 1) {
    int o = (t >= off) ? s[t - off] : 0;
    __syncthreads();
    s[t] += o;
    __syncthreads();
  }
  int offp = partials[b] + s[t] - local;
  if (base < N)     { rowptr[base] = offp;          cursor[base] = offp; }
  if (base + 1 < N) { rowptr[base + 1] = offp + d0; cursor[base + 1] = offp + d0; }
  if (b == 0 && t == 0) rowptr[N] = E;
}

__global__ void csr_scatter(const int* __restrict__ ei, int* __restrict__ cursor,
                            int* __restrict__ adj, int E) {
  int e = blockIdx.x * 256 + threadIdx.x;
  if (e < E) {
    int dst = ei[E + e];
    int pos = atomicAdd(&cursor[dst], 1);
    adj[pos] = ei[e];
  }
}

// ---------------- fused 4-projection GEMM (proven R12 shape, y=1) ------------
// mode 0: stage fp32 x -> bf16.  mode 1: stage fp16 H with BN+ReLU -> bf16.
struct GemmOut { _Float16* Y[4]; const float* bias[4]; };

#define LDP 136   // padded LDS row stride (bf16 elems)

__global__ __launch_bounds__(256) void gemm_proj(
    const float* __restrict__ Xf,
    const _Float16* __restrict__ Hin,
    const float* __restrict__ scale, const float* __restrict__ shift,
    const unsigned short* __restrict__ WB4,   // fragment-ordered, 4 mats x 16384
    GemmOut go, int useBN, int N)
{
  __shared__ __align__(16) unsigned short xs[64 * LDP];

  const int t = threadIdx.x;
  const int rowBase = blockIdx.x * 64;
  const int igc = (t & 15) * 8;

  if (useBN) {
    float4 sc0 = *reinterpret_cast<const float4*>(scale + igc);
    float4 sc1 = *reinterpret_cast<const float4*>(scale + igc + 4);
    float4 sh0 = *reinterpret_cast<const float4*>(shift + igc);
    float4 sh1 = *reinterpret_cast<const float4*>(shift + igc + 4);
#pragma unroll
    for (int j = 0; j < 4; ++j) {
      int v = t + 256 * j;
      int r = v >> 4;
      int grow = rowBase + r;
      ushort4 o0 = make_ushort4(0, 0, 0, 0), o1 = make_ushort4(0, 0, 0, 0);
      if (grow < N) {
        f16x8 hv = *reinterpret_cast<const f16x8*>(Hin + (size_t)grow * 128 + igc);
        o0.x = f2bf(fmaxf((float)hv[0] * sc0.x + sh0.x, 0.f));
        o0.y = f2bf(fmaxf((float)hv[1] * sc0.y + sh0.y, 0.f));
        o0.z = f2bf(fmaxf((float)hv[2] * sc0.z + sh0.z, 0.f));
        o0.w = f2bf(fmaxf((float)hv[3] * sc0.w + sh0.w, 0.f));
        o1.x = f2bf(fmaxf((float)hv[4] * sc1.x + sh1.x, 0.f));
        o1.y = f2bf(fmaxf((float)hv[5] * sc1.y + sh1.y, 0.f));
        o1.z = f2bf(fmaxf((float)hv[6] * sc1.z + sh1.z, 0.f));
        o1.w = f2bf(fmaxf((float)hv[7] * sc1.w + sh1.w, 0.f));
      }
      *reinterpret_cast<ushort4*>(&xs[r * LDP + igc]) = o0;
      *reinterpret_cast<ushort4*>(&xs[r * LDP + igc + 4]) = o1;
    }
  } else {
#pragma unroll
    for (int j = 0; j < 4; ++j) {
      int v = t + 256 * j;
      int r = v >> 4;
      int grow = rowBase + r;
      ushort4 o0 = make_ushort4(0, 0, 0, 0), o1 = make_ushort4(0, 0, 0, 0);
      if (grow < N) {
        float4 a = *reinterpret_cast<const float4*>(Xf + (size_t)grow * 128 + igc);
        float4 b = *reinterpret_cast<const float4*>(Xf + (size_t)grow * 128 + igc + 4);
        o0.x = f2bf(a.x); o0.y = f2bf(a.y); o0.z = f2bf(a.z); o0.w = f2bf(a.w);
        o1.x = f2bf(b.x); o1.y = f2bf(b.y); o1.z = f2bf(b.z); o1.w = f2bf(b.w);
      }
      *reinterpret_cast<ushort4*>(&xs[r * LDP + igc]) = o0;
      *reinterpret_cast<ushort4*>(&xs[r * LDP + igc + 4]) = o1;
    }
  }
  __syncthreads();

  const int wave = t >> 6;
  const int lane = t & 63;
  const int ln16 = lane & 15;
  const int quad = lane >> 4;
  const int r0 = wave * 16;

  bf16x8 afrag[4];
#pragma unroll
  for (int kk = 0; kk < 4; ++kk)
    afrag[kk] = *reinterpret_cast<const bf16x8*>(&xs[(r0 + ln16) * LDP + kk * 32 + quad * 8]);

  for (int proj = 0; proj < 4; ++proj) {
    const unsigned short* __restrict__ WB = WB4 + proj * 16384;
    const float* __restrict__ bias = go.bias[proj];

    f32x4 acc[8] = {};
#pragma unroll
    for (int kk = 0; kk < 4; ++kk) {
#pragma unroll
      for (int ct = 0; ct < 8; ++ct) {
        bf16x8 b = *reinterpret_cast<const bf16x8*>(WB + ((kk * 8 + ct) * 64 + lane) * 8);
        acc[ct] = __builtin_amdgcn_mfma_f32_16x16x32_bf16(afrag[kk], b, acc[ct], 0, 0, 0);
      }
    }

    _Float16* __restrict__ Yh = go.Y[proj];
#pragma unroll
    for (int ct = 0; ct < 8; ++ct) {
      int col = ct * 16 + ln16;
      float bv = bias[col];
#pragma unroll
      for (int reg = 0; reg < 4; ++reg) {
        int grow = rowBase + r0 + quad * 4 + reg;
        if (grow < N) Yh[(size_t)grow * 128 + col] = (_Float16)(acc[ct][reg] + bv);
      }
    }
  }
}

// ---------------- fused per-node attention + BN partial stats ----------------
// 16 lanes per node (f16x8 = 16B/lane), 16 nodes per 256-thread block.
__global__ __launch_bounds__(256) void node_attn(
    const int* __restrict__ rowptr, const int* __restrict__ adj,
    const _Float16* __restrict__ Q, const _Float16* __restrict__ K,
    const _Float16* __restrict__ V, _Float16* __restrict__ H,
    float* __restrict__ Pbuf, int N)
{
  __shared__ float lsum[16][128];
  __shared__ float lsq[16][128];
  int t = threadIdx.x;
  int w = t >> 4, lane = t & 15;
  int n = blockIdx.x * 16 + w;
  bool valid = n < N;
  int nn = valid ? n : 0;
  int p0 = 0, p1 = 0;
  if (valid) { p0 = rowptr[n]; p1 = rowptr[n + 1]; }

  f16x8 qv = *reinterpret_cast<const f16x8*>(Q + (size_t)nn * 128 + lane * 8);
  f16x2 q0 = {qv[0], qv[1]}, q1 = {qv[2], qv[3]}, q2 = {qv[4], qv[5]}, q3 = {qv[6], qv[7]};

  float m = -INFINITY, s = 0.f;
  float acc[8] = {};

  int p = p0;
  for (; p + 1 < p1; p += 2) {
    int s0 = adj[p], s1 = adj[p + 1];
    f16x8 k0 = *reinterpret_cast<const f16x8*>(K + (size_t)s0 * 128 + lane * 8);
    f16x8 k1 = *reinterpret_cast<const f16x8*>(K + (size_t)s1 * 128 + lane * 8);
    float d0 = fdot2acc(q0, (f16x2){k0[0], k0[1]},
               fdot2acc(q1, (f16x2){k0[2], k0[3]},
               fdot2acc(q2, (f16x2){k0[4], k0[5]},
               fdot2acc(q3, (f16x2){k0[6], k0[7]}, 0.f))));
    float d1 = fdot2acc(q0, (f16x2){k1[0], k1[1]},
               fdot2acc(q1, (f16x2){k1[2], k1[3]},
               fdot2acc(q2, (f16x2){k1[4], k1[5]},
               fdot2acc(q3, (f16x2){k1[6], k1[7]}, 0.f))));
#pragma unroll
    for (int off = 8; off; off >>= 1) {
      d0 += __shfl_xor(d0, off, 16);
      d1 += __shfl_xor(d1, off, 16);
    }
    float l0 = d0 * 0.08838834764831845f;
    float l1 = d1 * 0.08838834764831845f;
    float mn = fmaxf(m, fmaxf(l0, l1));
    float sc = __expf(m - mn);
    float w0 = __expf(l0 - mn);
    float w1 = __expf(l1 - mn);
    f16x8 v0 = *reinterpret_cast<const f16x8*>(V + (size_t)s0 * 128 + lane * 8);
    f16x8 v1 = *reinterpret_cast<const f16x8*>(V + (size_t)s1 * 128 + lane * 8);
#pragma unroll
    for (int i = 0; i < 8; ++i)
      acc[i] = acc[i] * sc + w0 * (float)v0[i] + w1 * (float)v1[i];
    s = s * sc + w0 + w1;
    m = mn;
  }
  if (p < p1) {
    int s0 = adj[p];
    f16x8 k0 = *reinterpret_cast<const f16x8*>(K + (size_t)s0 * 128 + lane * 8);
    float d0 = fdot2acc(q0, (f16x2){k0[0], k0[1]},
               fdot2acc(q1, (f16x2){k0[2], k0[3]},
               fdot2acc(q2, (f16x2){k0[4], k0[5]},
               fdot2acc(q3, (f16x2){k0[6], k0[7]}, 0.f))));
#pragma unroll
    for (int off = 8; off; off >>= 1) d0 += __shfl_xor(d0, off, 16);
    float l0 = d0 * 0.08838834764831845f;
    float mn = fmaxf(m, l0);
    float sc = __expf(m - mn);
    float w0 = __expf(l0 - mn);
    f16x8 v0 = *reinterpret_cast<const f16x8*>(V + (size_t)s0 * 128 + lane * 8);
#pragma unroll
    for (int i = 0; i < 8; ++i)
      acc[i] = acc[i] * sc + w0 * (float)v0[i];
    s = s * sc + w0;
    m = mn;
  }

  float h[8];
#pragma unroll
  for (int i = 0; i < 8; ++i) h[i] = 0.f;
  if (valid) {
    float inv = 1.0f / (s + 1e-16f);
    f16x8 hh = *reinterpret_cast<const f16x8*>(H + (size_t)n * 128 + lane * 8);
    f16x8 ho;
#pragma unroll
    for (int i = 0; i < 8; ++i) {
      h[i] = (float)hh[i] + acc[i] * inv;
      ho[i] = (_Float16)h[i];
    }
    *reinterpret_cast<f16x8*>(H + (size_t)n * 128 + lane * 8) = ho;
  }

  // BN partial stats
#pragma unroll
  for (int i = 0; i < 8; i += 4) {
    float4 hv = make_float4(h[i], h[i + 1], h[i + 2], h[i + 3]);
    float4 h2 = make_float4(hv.x * hv.x, hv.y * hv.y, hv.z * hv.z, hv.w * hv.w);
    *reinterpret_cast<float4*>(&lsum[w][lane * 8 + i]) = hv;
    *reinterpret_cast<float4*>(&lsq[w][lane * 8 + i]) = h2;
  }
  __syncthreads();

  int f = t & 127;
  float a = 0.f;
  if (t < 128) {
#pragma unroll
    for (int n16 = 0; n16 < 16; ++n16) a += lsum[n16][f];
  } else {
#pragma unroll
    for (int n16 = 0; n16 < 16; ++n16) a += lsq[n16][f];
  }
  Pbuf[(size_t)blockIdx.x * 256 + t] = a;
}

// ---------------- single-kernel BN reduce (last-block finalize) --------------
__global__ __launch_bounds__(256) void bn_reduce(
    const float* __restrict__ Pbuf, float* __restrict__ partial,
    int* __restrict__ counter,
    const float* __restrict__ gamma, const float* __restrict__ beta,
    float* __restrict__ scale, float* __restrict__ shift, int N)
{
  int t = threadIdx.x;
  float s0 = 0.f, s1 = 0.f, s2 = 0.f, s3 = 0.f;
  int r = blockIdx.x;
  for (; r + 192 < ATTN_BLOCKS; r += 256) {
    s0 += Pbuf[(size_t)(r      ) * 256 + t];
    s1 += Pbuf[(size_t)(r +  64) * 256 + t];
    s2 += Pbuf[(size_t)(r + 128) * 256 + t];
    s3 += Pbuf[(size_t)(r + 192) * 256 + t];
  }
  for (; r < ATTN_BLOCKS; r += 64) s0 += Pbuf[(size_t)r * 256 + t];
  partial[blockIdx.x * 256 + t] = s0 + s1 + s2 + s3;

  // last-block finalize (rocPRIM pattern: release fence + device atomic)
  __threadfence();
  __shared__ int isLast;
  if (t == 0) isLast = (atomicAdd(counter, 1) == 63);
  __syncthreads();
  if (!isLast) return;
  __threadfence();   // acquire side

  __shared__ float red[256];
  float a0 = 0.f, a1 = 0.f, a2 = 0.f, a3 = 0.f;
#pragma unroll
  for (int b = 0; b < 64; b += 4) {
    a0 += partial[(b + 0) * 256 + t];
    a1 += partial[(b + 1) * 256 + t];
    a2 += partial[(b + 2) * 256 + t];
    a3 += partial[(b + 3) * 256 + t];
  }
  red[t] = a0 + a1 + a2 + a3;
  __syncthreads();
  if (t == 0) *counter = 0;   // reset for next layer (kernel-boundary ordered)
  if (t < 128) {
    float mean = red[t] / (float)N;
    float var = red[t + 128] / (float)N - mean * mean;
    var = fmaxf(var, 0.f);
    float sc = gamma[t] * rsqrtf(var + 1e-5f);
    scale[t] = sc;
    shift[t] = beta[t] - mean * sc;
  }
}

// ---------------- parallel pool: 64-row chunks, flush at graph boundaries ----
__global__ __launch_bounds__(256) void pool_chunk(
    const _Float16* __restrict__ H, const float* __restrict__ scale,
    const float* __restrict__ shift, const int* __restrict__ batch,
    float* __restrict__ pooled, int N)
{
  int f = threadIdx.x & 127, half = threadIdx.x >> 7;
  int base = blockIdx.x * 64;
  int lim = min(base + 64, N);
  float sc = scale[f], sh = shift[f];
  int curg = -1; float s = 0.f;
  for (int row = base + half; row < lim; row += 2) {
    int g = batch[row];
    if (g != curg) {
      if (curg >= 0) unsafeAtomicAdd(pooled + curg * 128 + f, s);
      curg = g; s = 0.f;
    }
    s += fmaxf((float)H[(size_t)row * 128 + f] * sc + sh, 0.f);
  }
  if (curg >= 0) unsafeAtomicAdd(pooled + curg * 128 + f, s);
}

// ---------------- final linear -----------------------------------------------
__global__ __launch_bounds__(64) void final_linear(
    const float* __restrict__ pooled, const int* __restrict__ batch,
    const float* __restrict__ Wlin, const float* __restrict__ blin,
    float* __restrict__ out, int N)
{
  int g = blockIdx.x;
  int c = threadIdx.x;
  int lo = 0, hi = N;
  while (lo < hi) { int mid = (lo + hi) >> 1; if (batch[mid] < g) lo = mid + 1; else hi = mid; }
  int start = lo;
  hi = N;
  while (lo < hi) { int mid = (lo + hi) >> 1; if (batch[mid] < g + 1) lo = mid + 1; else hi = mid; }
  float inv = 1.0f / fmaxf((float)(lo - start), 1.f);
  if (c < 20) {
    float acc = 0.f;
#pragma unroll 4
    for (int i = 0; i < 128; ++i)
      acc += pooled[g * 128 + i] * Wlin[i * 20 + c];
    out[g * 20 + c] = acc * inv + blin[c];
  }
}

// =============================================================================
extern "C" void kernel_launch(void* const* d_in, const int* in_sizes, int n_in,
                              void* d_out, int out_size, void* d_ws, size_t ws_size,
                              hipStream_t stream)
{
  const int N = N_NODES, E = N_EDGES, G = N_GRAPHS;

  const float* x = (const float*)d_in[0];
  const int* ei = (const int*)d_in[1];
  const int* batch = (const int*)d_in[2];
  const float* Wlin = (const float*)d_in[33];
  const float* blin = (const float*)d_in[34];

  char* ws = (char*)d_ws;
  size_t off = 0;
  auto alloc = [&](size_t bytes) -> void* {
    void* p = ws + off;
    off = (off + bytes + 255) & ~(size_t)255;
    return p;
  };
  unsigned short* WB = (unsigned short*)alloc(12 * 16384 * sizeof(unsigned short));
  _Float16* Qh  = (_Float16*)alloc((size_t)N * 128 * 2);
  _Float16* Kh  = (_Float16*)alloc((size_t)N * 128 * 2);
  _Float16* Vh  = (_Float16*)alloc((size_t)N * 128 * 2);
  _Float16* Hh  = (_Float16*)alloc((size_t)N * 128 * 2);
  int* deg      = (int*)alloc((size_t)N * 4);
  int* rowptr   = (int*)alloc((size_t)(N + 1) * 4);
  int* cursor   = (int*)alloc((size_t)N * 4);
  int* adj      = (int*)alloc((size_t)E * 4);
  int* partials = (int*)alloc((size_t)N_CHUNKS * 4);
  int* counter  = (int*)alloc(256);
  float* Pbuf   = (float*)alloc((size_t)ATTN_BLOCKS * 256 * 4);
  float* bnpart = (float*)alloc((size_t)64 * 256 * 4);
  float* scale  = (float*)alloc(128 * 4);
  float* shift  = (float*)alloc(128 * 4);
  float* pooled = (float*)alloc((size_t)G * 128 * 4);

  // ---- one-time per launch: weight repack (+deg/counter init), CSR build ----
  WPtrs wp;
  for (int L = 0; L < 3; ++L) {
    wp.w[L * 4 + 0] = (const float*)d_in[3 + L * 10 + 0];  // Wq
    wp.w[L * 4 + 1] = (const float*)d_in[3 + L * 10 + 2];  // Wk
    wp.w[L * 4 + 2] = (const float*)d_in[3 + L * 10 + 4];  // Wv
    wp.w[L * 4 + 3] = (const float*)d_in[3 + L * 10 + 6];  // Ws
  }
  repack_kernel<<<dim3(64, 12), 256, 0, stream>>>(wp, WB, deg, counter, N);

  deg_count<<<(E + 255) / 256, 256, 0, stream>>>(ei, deg, E);
  scan_sum<<<N_CHUNKS, 256, 0, stream>>>(deg, partials, N);
  scan_partials<<<1, 128, 0, stream>>>(partials);
  scan_apply<<<N_CHUNKS, 256, 0, stream>>>(deg, partials, rowptr, cursor, N, E);
  csr_scatter<<<(E + 255) / 256, 256, 0, stream>>>(ei, cursor, adj, E);
  hipMemsetAsync(pooled, 0, (size_t)G * 128 * 4, stream);

  for (int L = 0; L < 3; ++L) {
    GemmOut go;
    go.Y[0] = Qh; go.Y[1] = Kh; go.Y[2] = Vh; go.Y[3] = Hh;
    go.bias[0] = (const float*)d_in[3 + L * 10 + 1];
    go.bias[1] = (const float*)d_in[3 + L * 10 + 3];
    go.bias[2] = (const float*)d_in[3 + L * 10 + 5];
    go.bias[3] = (const float*)d_in[3 + L * 10 + 7];
    gemm_proj<<<(N + 63) / 64, 256, 0, stream>>>(
        x, Hh, scale, shift, WB + L * 4 * 16384, go, (L > 0) ? 1 : 0, N);

    node_attn<<<ATTN_BLOCKS, 256, 0, stream>>>(rowptr, adj, Qh, Kh, Vh, Hh, Pbuf, N);

    bn_reduce<<<64, 256, 0, stream>>>(Pbuf, bnpart, counter,
        (const float*)d_in[3 + L * 10 + 8],
        (const float*)d_in[3 + L * 10 + 9],
        scale, shift, N);

    if (L == 2) {
      pool_chunk<<<POOL_CHUNKS, 256, 0, stream>>>(Hh, scale, shift, batch, pooled, N);
      final_linear<<<G, 64, 0, stream>>>(pooled, batch, Wlin, blin, (float*)d_out, N);
    }
  }
}